// Round 10
// baseline (102.690 us; speedup 1.0000x reference)
//
#include <hip/hip_runtime.h>
#include <math.h>

#define KM 192
#define EPSF 1e-6f
#define QMIN 0.5f
#define BLKA 256
#define HA 4
#define TILEA (BLKA * HA)    // 1024 hits per argmax tile
#define BLKM 256
#define NTILES 128           // main tiles per event (512 blocks total)

__device__ __forceinline__ float clipb(float b) {
    return fminf(fmaxf(b, 1e-4f), 1.0f - 1e-4f);
}
// atanh(b) = 0.5*ln((1+b)/(1-b)); b in [1e-4, 1-1e-4]
__device__ __forceinline__ float fast_atanh(float b) {
    float r = (1.f + b) * __builtin_amdgcn_rcpf(1.f - b);
    return 0.34657359f * __builtin_amdgcn_logf(r);
}
// broadcast lane j's value to all lanes via v_readlane (SGPR result)
__device__ __forceinline__ float bcast(float v, int j) {
    return __int_as_float(__builtin_amdgcn_readlane(__float_as_int(v), j));
}

// ---- K1: per-tile argmax partials into scratch (no global atomics) ----
// pack = (bits(clip(beta)) << 32) | (N-1-i): beta>0 -> bits monotone; low word
// reproduces jnp.argmax first-index tiebreak. argmax(beta) == argmax(q).
__global__ void __launch_bounds__(BLKA)
k_amax(const float* __restrict__ beta, const int* __restrict__ tidx,
       unsigned long long* __restrict__ pscr, int N, int HBT) {
    const int e = blockIdx.y;
    __shared__ unsigned long long smax[KM];
    for (int k = threadIdx.x; k < KM; k += BLKA) smax[k] = 0ull;
    __syncthreads();
    const size_t base = (size_t)e * N;
    #pragma unroll
    for (int h = 0; h < HA; ++h) {
        int i = blockIdx.x * TILEA + h * BLKA + threadIdx.x;
        if (i < N) {
            int t = tidx[base + i];
            if (t > 0) {
                float bc = clipb(beta[base + i]);
                unsigned long long pack =
                    ((unsigned long long)__float_as_uint(bc) << 32) |
                    (unsigned long long)(unsigned)(N - 1 - i);
                atomicMax(&smax[t], pack);
            }
        }
    }
    __syncthreads();
    unsigned long long* row = pscr + ((size_t)e * HBT + blockIdx.x) * KM;
    for (int k = threadIdx.x; k < KM; k += BLKA) row[k] = smax[k];
}

// ---- K2: build alpha table (x, y, q_a*valid); zero enm/eden/scal ----
__global__ void __launch_bounds__(256)
k_alpha(const unsigned long long* __restrict__ pscr, const float* __restrict__ cc,
        float4* __restrict__ alpha, float* __restrict__ abw,
        float* __restrict__ enm, float* __restrict__ eden,
        float* __restrict__ scal, int N, int HBT) {
    const int e = blockIdx.x;
    const int k = threadIdx.x;
    if (k < KM) {
        const unsigned long long* pk = pscr + (size_t)e * HBT * KM + k;
        unsigned long long v = 0ull;
        #pragma unroll 8
        for (int t = 0; t < HBT; ++t) {
            unsigned long long p = pk[(size_t)t * KM];
            if (p > v) v = p;
        }
        float4 a = make_float4(0.f, 0.f, 0.f, 0.f);
        float bw = 0.f;
        if (v) {
            int idx = N - 1 - (int)(unsigned)(v & 0xffffffffull);
            bw = __uint_as_float((unsigned)(v >> 32));     // clipped beta_alpha
            float at = fast_atanh(bw);
            float2 cp = ((const float2*)cc)[(size_t)e * N + idx];
            a.x = cp.x; a.y = cp.y;
            a.z = fmaf(at, at, QMIN);                      // q_alpha (0 => invalid)
        }
        alpha[e * KM + k] = a;
        abw  [e * KM + k] = bw;
    }
    for (int z = threadIdx.x; z < KM; z += 256) {
        enm [e * KM + z] = 0.f;
        eden[e * KM + z] = 0.f;
    }
    if (threadIdx.x < 8) scal[e * 8 + threadIdx.x] = 0.f;
}

// ---- K3: object-owner main pass. Each lane holds 3 objects in registers;
//      hits are broadcast lane-by-lane via v_readlane (no memory in inner loop).
//      rep separability: sum_i q_i sum_k hinge*q_k = sum_k q_k * sum_i q_i*hinge.
//      att + own-hinge + energy + noise handled in hit-parallel prologue. ----
__global__ void __launch_bounds__(BLKM, 4)
k_main(const float* __restrict__ beta, const float* __restrict__ cc,
       const float* __restrict__ pe,   const float* __restrict__ te,
       const int* __restrict__ tidx,   const float4* __restrict__ alpha,
       float* __restrict__ enm, float* __restrict__ eden,
       float* __restrict__ scal, int N) {
    const int e = blockIdx.y;
    const int lane = threadIdx.x & 63;
    __shared__ float sn[KM], sd[KM];
    __shared__ float sw[12];
    for (int k = threadIdx.x; k < KM; k += BLKM) { sn[k] = 0.f; sd[k] = 0.f; }

    const float4* __restrict__ ae = alpha + e * KM;
    // my 3 objects (x, y, q) in registers; q=0 for invalid slots
    const float4 o0 = ae[lane];
    const float4 o1 = ae[lane + 64];
    const float4 o2 = ae[lane + 128];
    __syncthreads();

    const size_t base = (size_t)e * N;
    const int hpt   = (N + NTILES - 1) / NTILES;
    const int start = blockIdx.x * hpt;
    const int end   = min(start + hpt, N);
    const int nst   = (hpt + BLKM - 1) / BLKM;

    float r0 = 0.f, r1 = 0.f, r2 = 0.f;
    float lvh = 0.f, bn = 0.f, cn = 0.f;

    for (int s = 0; s < nst; ++s) {
        const int i = start + s * BLKM + (int)threadIdx.x;
        const bool ok = i < end;
        const size_t ii = base + (ok ? i : 0);
        const float2 cp = ((const float2*)cc)[ii];
        const float  bc = clipb(beta[ii]);
        const int    t  = ok ? tidx[ii] : -1;
        const float  at = fast_atanh(bc);
        const float  qh = ok ? fmaf(at, at, QMIN) : 0.f;   // 0 kills invalid lanes

        if (t > 0) {      // member hit: att + own-hinge correction + energy
            float4 av = ae[t];                              // divergent, L1 (3KB)
            float dx = cp.x - av.x, dy = cp.y - av.y;
            float d2 = fmaf(dx, dx, dy * dy);
            float hin = fmaxf(1.f - __builtin_amdgcn_sqrtf(d2 + EPSF), 0.f);
            lvh = fmaf(qh * av.z, d2 - hin, lvh);
            float tev = te[ii];
            float edv = (pe[ii] - tev) * __builtin_amdgcn_rcpf(tev + 1.f);
            float ad  = fabsf(edv);
            float eh  = (ad <= 2.f) ? 0.5f * ad * ad : 2.f * (ad - 1.f);
            atomicAdd(&sn[t], bc * eh);
            atomicAdd(&sd[t], bc);
        } else if (t == 0) { bn += bc; cn += 1.f; }

        // broadcast loop: hit j of this wave's 64-hit batch vs my 3 objects
        #pragma unroll 16
        for (int j = 0; j < 64; ++j) {
            const float xh = bcast(cp.x, j);
            const float yh = bcast(cp.y, j);
            const float qb = bcast(qh,  j);
            float dx0 = o0.x - xh, dy0 = o0.y - yh;
            float dx1 = o1.x - xh, dy1 = o1.y - yh;
            float dx2 = o2.x - xh, dy2 = o2.y - yh;
            float d0 = fmaf(dx0, dx0, fmaf(dy0, dy0, EPSF));
            float d1 = fmaf(dx1, dx1, fmaf(dy1, dy1, EPSF));
            float d2 = fmaf(dx2, dx2, fmaf(dy2, dy2, EPSF));
            r0 = fmaf(fmaxf(1.f - __builtin_amdgcn_sqrtf(d0), 0.f), qb, r0);
            r1 = fmaf(fmaxf(1.f - __builtin_amdgcn_sqrtf(d1), 0.f), qb, r1);
            r2 = fmaf(fmaxf(1.f - __builtin_amdgcn_sqrtf(d2), 0.f), qb, r2);
        }
    }

    // q_k-weighted rep totals + per-hit terms
    float lv = fmaf(o0.z, r0, fmaf(o1.z, r1, fmaf(o2.z, r2, lvh)));
    __syncthreads();

    if (threadIdx.x < KM) {
        float vd = sd[threadIdx.x];
        if (vd != 0.f) {
            atomicAdd(&enm [e * KM + threadIdx.x], sn[threadIdx.x]);
            atomicAdd(&eden[e * KM + threadIdx.x], vd);
        }
    }
    for (int off = 32; off > 0; off >>= 1) {
        lv += __shfl_down(lv, off);
        bn += __shfl_down(bn, off);
        cn += __shfl_down(cn, off);
    }
    const int wid = threadIdx.x >> 6;
    if ((threadIdx.x & 63) == 0) { sw[wid] = lv; sw[4 + wid] = bn; sw[8 + wid] = cn; }
    __syncthreads();
    if (threadIdx.x == 0) {
        atomicAdd(&scal[e * 8 + 0], (sw[0] + sw[1]) + (sw[2] + sw[3]));
        atomicAdd(&scal[e * 8 + 3], (sw[4] + sw[5]) + (sw[6] + sw[7]));
        atomicAdd(&scal[e * 8 + 4], (sw[8] + sw[9]) + (sw[10] + sw[11]));
    }
}

// ---- K4: finalize (1 block) ----
__global__ void __launch_bounds__(256)
k_fin(const float* __restrict__ enm, const float* __restrict__ eden,
      const float* __restrict__ abw, const float* __restrict__ scal,
      float* __restrict__ out, int N, int B) {
    __shared__ float sred[12];
    const int wid = threadIdx.x >> 6;
    float tot = 0.f;
    for (int ev = 0; ev < B; ++ev) {
        float lb = 0.f, nv = 0.f, le = 0.f;
        if (threadIdx.x < KM) {
            float bw = abw[ev * KM + threadIdx.x];
            if (bw > 0.f) {
                lb = 1.f - bw;
                nv = 1.f;
                le = enm[ev * KM + threadIdx.x] / (eden[ev * KM + threadIdx.x] + EPSF);
            }
        }
        for (int off = 32; off > 0; off >>= 1) {
            lb += __shfl_down(lb, off);
            nv += __shfl_down(nv, off);
            le += __shfl_down(le, off);
        }
        if ((threadIdx.x & 63) == 0) { sred[wid] = lb; sred[4 + wid] = nv; sred[8 + wid] = le; }
        __syncthreads();
        if (threadIdx.x == 0) {
            float lbs = (sred[0] + sred[1]) + (sred[2] + sred[3]);
            float nvs = (sred[4] + sred[5]) + (sred[6] + sred[7]);
            float les = (sred[8] + sred[9]) + (sred[10] + sred[11]);
            float nobj = nvs + EPSF;
            tot += scal[ev * 8 + 0] / (float)N + lbs / nobj
                 + scal[ev * 8 + 3] / (scal[ev * 8 + 4] + EPSF) + les / nobj;
        }
        __syncthreads();
    }
    if (threadIdx.x == 0) out[0] = tot / (float)B;
}

extern "C" void kernel_launch(void* const* d_in, const int* in_sizes, int n_in,
                              void* d_out, int out_size, void* d_ws, size_t ws_size,
                              hipStream_t stream) {
    const int B = 4;
    const int N = in_sizes[0] / B;               // beta is [B,N,1]
    const int HBT = (N + TILEA - 1) / TILEA;     // argmax tiles of 1024

    const float* beta = (const float*)d_in[0];
    const float* cc   = (const float*)d_in[1];
    const float* pe   = (const float*)d_in[2];
    const float* te   = (const float*)d_in[3];
    const int*   tidx = (const int*)  d_in[4];
    float* out = (float*)d_out;

    // ws: pscr u64[B*HBT*KM] | alpha float4[B*KM] | abw f32[B*KM]
    //     | enm f32[B*KM] | eden f32[B*KM] | scal f32[B*8]
    char* ws = (char*)d_ws;
    unsigned long long* pscr = (unsigned long long*)ws;
    float4* alpha = (float4*)(ws + (size_t)B * HBT * KM * 8);
    float*  abw   = (float*)(alpha + B * KM);
    float*  enm   = abw  + B * KM;
    float*  eden  = enm  + B * KM;
    float*  scal  = eden + B * KM;

    k_amax<<<dim3(HBT, B), dim3(BLKA), 0, stream>>>(beta, tidx, pscr, N, HBT);
    k_alpha<<<dim3(B), dim3(256), 0, stream>>>(pscr, cc, alpha, abw, enm, eden, scal, N, HBT);
    k_main<<<dim3(NTILES, B), dim3(BLKM), 0, stream>>>(
        beta, cc, pe, te, tidx, alpha, enm, eden, scal, N);
    k_fin<<<dim3(1), dim3(256), 0, stream>>>(enm, eden, abw, scal, out, N, B);
}

// Round 11
// 95.271 us; speedup vs baseline: 1.0779x; 1.0779x over previous
//
#include <hip/hip_runtime.h>
#include <math.h>

#define KM 192
#define EPSF 1e-6f
#define QMIN 0.5f
#define BLK 256
#define HA 4
#define TILEA (BLK * HA)     // 1024 hits per K1 tile

__device__ __forceinline__ float clipb(float b) {
    return fminf(fmaxf(b, 1e-4f), 1.0f - 1e-4f);
}
// atanh(b) = 0.5*ln((1+b)/(1-b)); b in [1e-4, 1-1e-4]
__device__ __forceinline__ float fast_atanh(float b) {
    float r = (1.f + b) * __builtin_amdgcn_rcpf(1.f - b);
    return 0.34657359f * __builtin_amdgcn_logf(r);
}
// broadcast lane j's value to all lanes (v_readlane -> SGPR)
__device__ __forceinline__ float bcast(float v, int j) {
    return __int_as_float(__builtin_amdgcn_readlane(__float_as_int(v), j));
}

// ---- K1: all alpha-independent work in one pass ----
// per-block LDS argmax -> global atomicMax packs (<=192 atomics/block);
// energy Huber num/den -> LDS -> global atomicAdd; noise sums -> scal.
// pack = (bits(clip(beta)) << 32) | (N-1-i): beta>0 -> bits monotone; low word
// reproduces jnp.argmax first-index tiebreak. argmax(beta) == argmax(q).
__global__ void __launch_bounds__(BLK)
k_pre(const float* __restrict__ beta, const int* __restrict__ tidx,
      const float* __restrict__ pe,   const float* __restrict__ te,
      unsigned long long* __restrict__ packs,
      float* __restrict__ enm, float* __restrict__ eden,
      float* __restrict__ scal, int N) {
    const int e = blockIdx.y;
    __shared__ unsigned long long smax[KM];
    __shared__ float sn[KM], sd[KM];
    __shared__ float sw[8];
    if (threadIdx.x < KM) { smax[threadIdx.x] = 0ull; sn[threadIdx.x] = 0.f; sd[threadIdx.x] = 0.f; }
    __syncthreads();

    const size_t base = (size_t)e * N;
    float bn = 0.f, cn = 0.f;
    #pragma unroll
    for (int h = 0; h < HA; ++h) {
        int i = blockIdx.x * TILEA + h * BLK + threadIdx.x;
        if (i < N) {
            int   t  = tidx[base + i];
            float bc = clipb(beta[base + i]);
            if (t > 0) {
                unsigned long long pack =
                    ((unsigned long long)__float_as_uint(bc) << 32) |
                    (unsigned long long)(unsigned)(N - 1 - i);
                atomicMax(&smax[t], pack);
                float tev = te[base + i];
                float edv = (pe[base + i] - tev) * __builtin_amdgcn_rcpf(tev + 1.f);
                float ad  = fabsf(edv);
                float eh  = (ad <= 2.f) ? 0.5f * ad * ad : 2.f * (ad - 1.f);
                atomicAdd(&sn[t], bc * eh);
                atomicAdd(&sd[t], bc);
            } else { bn += bc; cn += 1.f; }
        }
    }
    __syncthreads();

    if (threadIdx.x < KM) {
        unsigned long long v = smax[threadIdx.x];
        if (v) atomicMax(&packs[e * KM + threadIdx.x], v);
        float vd = sd[threadIdx.x];
        if (vd != 0.f) {
            atomicAdd(&enm [e * KM + threadIdx.x], sn[threadIdx.x]);
            atomicAdd(&eden[e * KM + threadIdx.x], vd);
        }
    }
    for (int off = 32; off > 0; off >>= 1) {
        bn += __shfl_down(bn, off);
        cn += __shfl_down(cn, off);
    }
    const int wid = threadIdx.x >> 6;
    if ((threadIdx.x & 63) == 0) { sw[wid] = bn; sw[4 + wid] = cn; }
    __syncthreads();
    if (threadIdx.x == 0) {
        atomicAdd(&scal[e * 8 + 3], (sw[0] + sw[1]) + (sw[2] + sw[3]));
        atomicAdd(&scal[e * 8 + 4], (sw[4] + sw[5]) + (sw[6] + sw[7]));
    }
}

// ---- K2: per-block alpha rebuild (plain loads; kernel-boundary coherence) +
//      object-owner readlane rep-loop + member terms + last-block finalize ----
__global__ void __launch_bounds__(BLK, 4)
k_main(const float* __restrict__ beta, const float* __restrict__ cc,
       const int* __restrict__ tidx,
       const unsigned long long* __restrict__ packs,
       float* __restrict__ abw,
       const float* __restrict__ enm, const float* __restrict__ eden,
       float* __restrict__ scal, unsigned int* __restrict__ cnt,
       float* __restrict__ out, int N, int B) {
    const int e = blockIdx.y;
    __shared__ float4 sa[KM];           // (x_a, y_a, q_a*valid, beta_a)
    __shared__ float  sw[12];
    __shared__ int    lastFlag;

    if (threadIdx.x < KM) {
        unsigned long long v = packs[e * KM + threadIdx.x];   // coalesced, L2-hot
        float4 a = make_float4(0.f, 0.f, 0.f, 0.f);
        if (v) {
            int idx  = N - 1 - (int)(unsigned)(v & 0xffffffffull);
            float bw = __uint_as_float((unsigned)(v >> 32));  // clipped beta_alpha
            float at = fast_atanh(bw);
            float2 cp = ((const float2*)cc)[(size_t)e * N + idx];
            a = make_float4(cp.x, cp.y, fmaf(at, at, QMIN), bw);
        }
        sa[threadIdx.x] = a;
        if (blockIdx.x == 0) abw[e * KM + threadIdx.x] = a.w;
    }
    __syncthreads();

    const int lane = threadIdx.x & 63;
    const float4 o0 = sa[lane];          // my 3 objects in registers
    const float4 o1 = sa[lane + 64];
    const float4 o2 = sa[lane + 128];

    const size_t base = (size_t)e * N;
    const int i = blockIdx.x * BLK + threadIdx.x;
    const bool ok = i < N;
    const size_t ii = base + (ok ? i : 0);
    const float2 cp = ((const float2*)cc)[ii];
    const float  bc = clipb(beta[ii]);
    const int    t  = ok ? tidx[ii] : -1;
    const float  at = fast_atanh(bc);
    const float  qh = ok ? fmaf(at, at, QMIN) : 0.f;   // 0 kills pad-hit terms

    float lvh = 0.f;
    if (t > 0) {                         // member: att + own-hinge correction
        float4 av = sa[t];               // LDS gather (divergent, cheap)
        float dx = cp.x - av.x, dy = cp.y - av.y;
        float d2 = fmaf(dx, dx, dy * dy);
        float hin = fmaxf(1.f - __builtin_amdgcn_sqrtf(d2 + EPSF), 0.f);
        lvh = qh * av.z * (d2 - hin);
    }

    // rep separability: sum_i q_i sum_k hinge*q_k = sum_k q_k (sum_i q_i*hinge).
    // hits broadcast lane-by-lane; zero memory ops in the loop.
    float r0 = 0.f, r1 = 0.f, r2 = 0.f;
    #pragma unroll 16
    for (int j = 0; j < 64; ++j) {
        const float xh = bcast(cp.x, j);
        const float yh = bcast(cp.y, j);
        const float qb = bcast(qh,  j);
        float dx0 = o0.x - xh, dy0 = o0.y - yh;
        float dx1 = o1.x - xh, dy1 = o1.y - yh;
        float dx2 = o2.x - xh, dy2 = o2.y - yh;
        float d0 = fmaf(dx0, dx0, fmaf(dy0, dy0, EPSF));
        float d1 = fmaf(dx1, dx1, fmaf(dy1, dy1, EPSF));
        float d2 = fmaf(dx2, dx2, fmaf(dy2, dy2, EPSF));
        r0 = fmaf(fmaxf(1.f - __builtin_amdgcn_sqrtf(d0), 0.f), qb, r0);
        r1 = fmaf(fmaxf(1.f - __builtin_amdgcn_sqrtf(d1), 0.f), qb, r1);
        r2 = fmaf(fmaxf(1.f - __builtin_amdgcn_sqrtf(d2), 0.f), qb, r2);
    }
    float lv = fmaf(o0.z, r0, fmaf(o1.z, r1, fmaf(o2.z, r2, lvh)));
    __syncthreads();

    for (int off = 32; off > 0; off >>= 1) lv += __shfl_down(lv, off);
    const int wid = threadIdx.x >> 6;
    if ((threadIdx.x & 63) == 0) sw[wid] = lv;
    __syncthreads();
    if (threadIdx.x == 0)
        atomicAdd(&scal[e * 8 + 0], (sw[0] + sw[1]) + (sw[2] + sw[3]));

    // ---- last-block-done finalize ----
    if (threadIdx.x == 0) {
        __threadfence();
        unsigned int old = atomicAdd(&cnt[0], 1u);
        lastFlag = (old == gridDim.x * gridDim.y - 1u);
    }
    __syncthreads();
    if (!lastFlag) return;
    __threadfence();

    volatile float* vab = abw;
    volatile float* vsc = scal;
    float tot = 0.f;
    for (int ev = 0; ev < B; ++ev) {
        float lb = 0.f, nv = 0.f, le = 0.f;
        if (threadIdx.x < KM) {
            float bw = vab[ev * KM + threadIdx.x];
            if (bw > 0.f) {
                lb = 1.f - bw;
                nv = 1.f;
                le = enm[ev * KM + threadIdx.x] / (eden[ev * KM + threadIdx.x] + EPSF);
            }
        }
        for (int off = 32; off > 0; off >>= 1) {
            lb += __shfl_down(lb, off);
            nv += __shfl_down(nv, off);
            le += __shfl_down(le, off);
        }
        if ((threadIdx.x & 63) == 0) { sw[wid] = lb; sw[4 + wid] = nv; sw[8 + wid] = le; }
        __syncthreads();
        if (threadIdx.x == 0) {
            float lbs = (sw[0] + sw[1]) + (sw[2] + sw[3]);
            float nvs = (sw[4] + sw[5]) + (sw[6] + sw[7]);
            float les = (sw[8] + sw[9]) + (sw[10] + sw[11]);
            float nobj = nvs + EPSF;
            tot += vsc[ev * 8 + 0] / (float)N + lbs / nobj
                 + vsc[ev * 8 + 3] / (vsc[ev * 8 + 4] + EPSF) + les / nobj;
        }
        __syncthreads();
    }
    if (threadIdx.x == 0) out[0] = tot / (float)B;
}

extern "C" void kernel_launch(void* const* d_in, const int* in_sizes, int n_in,
                              void* d_out, int out_size, void* d_ws, size_t ws_size,
                              hipStream_t stream) {
    const int B = 4;
    const int N = in_sizes[0] / B;               // beta is [B,N,1]
    const int HBT = (N + TILEA - 1) / TILEA;     // K1 tiles of 1024 (49)
    const int MB  = (N + BLK - 1) / BLK;         // K2 tiles of 256 (196)

    const float* beta = (const float*)d_in[0];
    const float* cc   = (const float*)d_in[1];
    const float* pe   = (const float*)d_in[2];
    const float* te   = (const float*)d_in[3];
    const int*   tidx = (const int*)  d_in[4];
    float* out = (float*)d_out;

    // ws: packs u64[B*KM] | abw f32[B*KM] | enm f32[B*KM] | eden f32[B*KM]
    //     | scal f32[B*8] | cnt u32[16]
    char* ws = (char*)d_ws;
    unsigned long long* packs = (unsigned long long*)ws;
    float* abw  = (float*)(ws + (size_t)B * KM * 8);
    float* enm  = abw  + B * KM;
    float* eden = enm  + B * KM;
    float* scal = eden + B * KM;
    unsigned int* cnt = (unsigned int*)(scal + B * 8);
    const size_t zeroBytes = (char*)(cnt + 16) - ws;   // ~15.6 KB

    (void)hipMemsetAsync(d_ws, 0, zeroBytes, stream);
    k_pre<<<dim3(HBT, B), dim3(BLK), 0, stream>>>(beta, tidx, pe, te, packs, enm, eden, scal, N);
    k_main<<<dim3(MB, B), dim3(BLK), 0, stream>>>(
        beta, cc, tidx, packs, abw, enm, eden, scal, cnt, out, N, B);
}